// Round 1
// 246.625 us; speedup vs baseline: 1.0247x; 1.0247x over previous
//
#include <hip/hip_runtime.h>
#include <cstddef>

// Problem constants (fixed by setup_inputs)
#define BB 4
#define QQ 4096
#define MM 8
#define NN 21760

typedef __bf16 bf16_8 __attribute__((ext_vector_type(8)));
typedef __bf16 bf16_4 __attribute__((ext_vector_type(4)));
typedef float  floatx4 __attribute__((ext_vector_type(4)));

// ---------------------------------------------------------------------------
// Weight prep: fp32 W[K][N] -> bf16 Wt[N][K].
// Wt layout (bf16): Wval[256x256] | Wq[384x256] (attn 0..127 | off 128..383) |
//                   Wout[256x256].  Also biasq[384] = [b_attn | b_off] fp32.
// ---------------------------------------------------------------------------
__global__ __launch_bounds__(256) void prep_weights(
    const float* __restrict__ Wv, const float* __restrict__ Wa,
    const float* __restrict__ Wo, const float* __restrict__ Wu,
    const float* __restrict__ ba, const float* __restrict__ bo,
    __bf16* __restrict__ Wt, float* __restrict__ biasq)
{
    const int gid = blockIdx.x * 256 + threadIdx.x;
    if (gid < 65536) {
        const int n = gid >> 8, k = gid & 255;
        Wt[gid] = (__bf16)Wv[k * 256 + n];
    } else if (gid < 163840) {
        const int o = gid - 65536;
        const int n = o >> 8, k = o & 255;
        Wt[gid] = (__bf16)(n < 128 ? Wa[k * 128 + n] : Wo[k * 256 + (n - 128)]);
    } else if (gid < 229376) {
        const int o = gid - 163840;
        const int n = o >> 8, k = o & 255;
        Wt[gid] = (__bf16)Wu[k * 256 + n];
    } else if (gid < 229760) {
        const int j = gid - 229376;
        biasq[j] = (j < 128) ? ba[j] : bo[j - 128];
    }
}

// ---------------------------------------------------------------------------
// Weight-stationary bf16 MFMA GEMM, occupancy-first variant.
// One 64-token tile per block (TILES=1): stage A-tile into a single 32 KB
// XOR-swizzled LDS buffer, ONE barrier, 8 k-steps of MFMA, store.  Feature
// dimension is sliced across blockIdx.x in chunks of NCB (128 or 256) so
// every launch has >= 2 blocks/CU co-resident (vs 340 blocks / 16% occupancy
// in the TILES=4 version, whose counters showed all pipes ~94% idle).
// Weight panel (NCB x 256 bf16) is loaded to VGPRs per block; the re-read
// across token-tiles is L2/L3-resident traffic we deliberately trade for
// 4x block-level parallelism.
// MODE 0: fp32 store at Cout[(z*tokens+token)*ldc + col]
// MODE 1: bf16 v_p store at [((z*8 + col/32)*NN + token)*32 + col%32]
// ---------------------------------------------------------------------------
template<typename AT, int NCB, int MODE>
__global__ __launch_bounds__(512, 4) void gemm_ws(
    const AT* __restrict__ A,
    const __bf16* __restrict__ Wn,     // [NCTOT][256] bf16 (n-major)
    const float* __restrict__ bias,    // [NCTOT] fp32
    void* __restrict__ Cout,
    int tokens, int ldc)
{
    constexpr int F  = NCB / 8;        // features per wave (16 or 32)
    constexpr int NJ = F / 16;         // feature frags per wave (1 or 2)

    const int z    = blockIdx.z;
    const int col0 = blockIdx.x * NCB; // feature-slice base
    const AT* Ab   = A + (size_t)z * tokens * 256;
    const __bf16* Wb = Wn + (size_t)col0 * 256;

    // XOR-swizzled activation tile: element (r, k) lives at column
    // ((k>>3) ^ (r&7))<<3 | (k&7).  Exactly 32 KB (64 x 256 bf16).
    __shared__ __bf16 As[64][256];

    const int tid  = threadIdx.x;
    const int lane = tid & 63;
    const int wave = tid >> 6;
    const int quad = lane >> 4;
    const int l16  = lane & 15;
    const int wave_f = wave * F;

    // ---- weights -> VGPRs, once per block ----
    bf16_8 wf[8][NJ];
    #pragma unroll
    for (int kk = 0; kk < 8; ++kk)
        #pragma unroll
        for (int j = 0; j < NJ; ++j)
            wf[kk][j] = *(const bf16_8*)(Wb + (size_t)(wave_f + j * 16 + l16) * 256
                                          + kk * 32 + quad * 8);

    // ---- stage the 64x256 activation tile ----
    const int token0 = blockIdx.y * 64;
    if (sizeof(AT) == 4) {
        const float* Af = (const float*)Ab;
        #pragma unroll
        for (int c = 0; c < 8; ++c) {
            const int cid = c * 512 + tid;
            const int r   = cid >> 6;
            const int kc  = (cid & 63) * 4;
            const float4 av = *(const float4*)(Af + (size_t)(token0 + r) * 256 + kc);
            bf16_4 w;
            w[0] = (__bf16)av.x; w[1] = (__bf16)av.y;
            w[2] = (__bf16)av.z; w[3] = (__bf16)av.w;
            const int col = ((((kc >> 3) ^ (r & 7)) << 3) | (kc & 7));
            *(bf16_4*)&As[r][col] = w;
        }
    } else {
        const __bf16* Ah = (const __bf16*)Ab;
        #pragma unroll
        for (int c = 0; c < 4; ++c) {
            const int cid = c * 512 + tid;
            const int r   = cid >> 5;
            const int kc  = (cid & 31) * 8;
            const bf16_8 av = *(const bf16_8*)(Ah + (size_t)(token0 + r) * 256 + kc);
            const int col = (((kc >> 3) ^ (r & 7)) << 3);
            *(bf16_8*)&As[r][col] = av;
        }
    }
    __syncthreads();

    // ---- MFMA over k = 0..255 ----
    floatx4 acc[NJ][4] = {};
    #pragma unroll
    for (int kk = 0; kk < 8; ++kk) {
        bf16_8 af[4];
        #pragma unroll
        for (int it = 0; it < 4; ++it)
            af[it] = *(const bf16_8*)&As[it * 16 + l16]
                                       [(((kk * 4 + quad) ^ (l16 & 7)) << 3)];
        #pragma unroll
        for (int j = 0; j < NJ; ++j)
            #pragma unroll
            for (int it = 0; it < 4; ++it)
                acc[j][it] = __builtin_amdgcn_mfma_f32_16x16x32_bf16(wf[kk][j], af[it], acc[j][it], 0, 0, 0);
    }

    // ---- epilogue: lane holds 4 consecutive features per frag ----
    #pragma unroll
    for (int j = 0; j < NJ; ++j) {
        const int n0 = col0 + wave_f + j * 16 + quad * 4;
        const float4 b4 = *(const float4*)(bias + n0);
        #pragma unroll
        for (int it = 0; it < 4; ++it) {
            const int token = token0 + it * 16 + l16;
            const float v0 = acc[j][it][0] + b4.x;
            const float v1 = acc[j][it][1] + b4.y;
            const float v2 = acc[j][it][2] + b4.z;
            const float v3 = acc[j][it][3] + b4.w;
            if (MODE == 0) {
                float4 o; o.x = v0; o.y = v1; o.z = v2; o.w = v3;
                *(float4*)((float*)Cout + ((size_t)z * tokens + token) * ldc + n0) = o;
            } else {
                const int mh = n0 >> 5, dd = n0 & 31;
                bf16_4 ob;
                ob[0] = (__bf16)v0; ob[1] = (__bf16)v1; ob[2] = (__bf16)v2; ob[3] = (__bf16)v3;
                *(bf16_4*)((__bf16*)Cout + (((size_t)z * 8 + mh) * NN + token) * 32 + dd) = ob;
            }
        }
    }
}

// ---------------------------------------------------------------------------
// Fused softmax + bilinear sampling (v4): 4-lanes-per-row gather +
// halving-tree shuffle reduction.  Block = 512 threads = 8 waves (wave = head).
// ---------------------------------------------------------------------------
__device__ __forceinline__ float bflo(unsigned u) { return __uint_as_float(u << 16); }
__device__ __forceinline__ float bfhi(unsigned u) { return __uint_as_float(u & 0xffff0000u); }

__global__ __launch_bounds__(512) void sampler(
    const __bf16* __restrict__ vp,    // [B,8,N,32] bf16
    const float* __restrict__ gqp,    // [B*Q,384]: 0..127 attn logits, 128..383 offsets
    const float* __restrict__ pref,   // [B*Q,4,2]
    __bf16* __restrict__ mid)         // [B*Q,256] bf16
{
    const int t    = threadIdx.x;
    const int m    = t >> 6;
    const int lane = t & 63;
    const int s    = lane >> 2;     // sample 0..15
    const int c    = lane & 3;      // 16B chunk 0..3
    const int l    = s >> 2;        // level
    const int bq   = blockIdx.x;
    const int b    = bq >> 12;      // Q = 4096

    const int   Hi = 128 >> l;      // 128,64,32,16 (square levels)
    const float Hf = (float)Hi;
    const int   base = (l == 0) ? 0 : (l == 1) ? 16384 : (l == 2) ? 20480 : 21504;

    // softmax over the 16 samples of this head (lane bits 2..5); logits O(1)
    const float logit = gqp[(size_t)bq * 384 + m * 16 + s];
    const float e = __expf(logit);
    float sum = e;
    #pragma unroll
    for (int k = 4; k < 64; k <<= 1) sum += __shfl_xor(sum, k, 64);
    const float a = e * __builtin_amdgcn_rcpf(sum);

    const float2 off = *(const float2*)(gqp + (size_t)bq * 384 + 128 + (m * 16 + s) * 2);
    const float2 pr  = *(const float2*)(pref + (size_t)bq * 8 + l * 2);

    const float x = fmaf(pr.x, Hf, off.x - 0.5f);
    const float y = fmaf(pr.y, Hf, off.y - 0.5f);
    const float x0f = floorf(x), y0f = floorf(y);
    const float lx = x - x0f, ly = y - y0f;
    const int x0 = (int)x0f, y0 = (int)y0f;
    const int cx0 = min(max(x0, 0), Hi - 1), cx1 = min(max(x0 + 1, 0), Hi - 1);
    const int cy0 = min(max(y0, 0), Hi - 1), cy1 = min(max(y0 + 1, 0), Hi - 1);
    const bool vx0 = (x0 >= 0) && (x0 < Hi), vx1 = (x0 + 1 >= 0) && (x0 + 1 < Hi);
    const bool vy0 = (y0 >= 0) && (y0 < Hi), vy1 = (y0 + 1 >= 0) && (y0 + 1 < Hi);
    const float w00 = a * (1.f - lx) * (1.f - ly) * ((vx0 && vy0) ? 1.f : 0.f);
    const float w10 = a * lx * (1.f - ly) * ((vx1 && vy0) ? 1.f : 0.f);
    const float w01 = a * (1.f - lx) * ly * ((vx0 && vy1) ? 1.f : 0.f);
    const float w11 = a * lx * ly * ((vx1 && vy1) ? 1.f : 0.f);

    const __bf16* vbase = vp + ((size_t)b * 8 + m) * NN * 32;
    const uint4 u00 = *((const uint4*)(vbase + (size_t)(base + cy0 * Hi + cx0) * 32) + c);
    const uint4 u10 = *((const uint4*)(vbase + (size_t)(base + cy0 * Hi + cx1) * 32) + c);
    const uint4 u01 = *((const uint4*)(vbase + (size_t)(base + cy1 * Hi + cx0) * 32) + c);
    const uint4 u11 = *((const uint4*)(vbase + (size_t)(base + cy1 * Hi + cx1) * 32) + c);

    float f[8];
    f[0] = w00*bflo(u00.x) + w10*bflo(u10.x) + w01*bflo(u01.x) + w11*bflo(u11.x);
    f[1] = w00*bfhi(u00.x) + w10*bfhi(u10.x) + w01*bfhi(u01.x) + w11*bfhi(u11.x);
    f[2] = w00*bflo(u00.y) + w10*bflo(u10.y) + w01*bflo(u01.y) + w11*bflo(u11.y);
    f[3] = w00*bfhi(u00.y) + w10*bfhi(u10.y) + w01*bfhi(u01.y) + w11*bfhi(u11.y);
    f[4] = w00*bflo(u00.z) + w10*bflo(u10.z) + w01*bflo(u01.z) + w11*bflo(u11.z);
    f[5] = w00*bfhi(u00.z) + w10*bfhi(u10.z) + w01*bfhi(u01.z) + w11*bfhi(u11.z);
    f[6] = w00*bflo(u00.w) + w10*bflo(u10.w) + w01*bflo(u01.w) + w11*bflo(u11.w);
    f[7] = w00*bfhi(u00.w) + w10*bfhi(u10.w) + w01*bfhi(u01.w) + w11*bfhi(u11.w);

    // Halving-tree reduction over the 16 samples (lane bits 2..5)
    const int b2 = (lane >> 2) & 1, b3 = (lane >> 3) & 1, b4i = (lane >> 4) & 1;
    #pragma unroll
    for (int j = 0; j < 4; ++j) {
        const float sel  = b2 ? f[j] : f[j + 4];
        const float recv = __shfl_xor(sel, 4, 64);
        f[j] = (b2 ? f[j + 4] : f[j]) + recv;
    }
    #pragma unroll
    for (int j = 0; j < 2; ++j) {
        const float sel  = b3 ? f[j] : f[j + 2];
        const float recv = __shfl_xor(sel, 8, 64);
        f[j] = (b3 ? f[j + 2] : f[j]) + recv;
    }
    {
        const float sel  = b4i ? f[0] : f[1];
        const float recv = __shfl_xor(sel, 16, 64);
        f[0] = (b4i ? f[1] : f[0]) + recv;
    }
    f[0] += __shfl_xor(f[0], 32, 64);

    if (!(lane & 32)) {
        const int chan = (c << 3) | (b2 << 2) | (b3 << 1) | b4i;
        mid[(size_t)bq * 256 + m * 32 + chan] = (__bf16)f[0];
    }
}

extern "C" void kernel_launch(void* const* d_in, const int* in_sizes, int n_in,
                              void* d_out, int out_size, void* d_ws, size_t ws_size,
                              hipStream_t stream) {
    const float* q      = (const float*)d_in[0];
    const float* p      = (const float*)d_in[1];
    const float* v      = (const float*)d_in[2];
    const float* W_off  = (const float*)d_in[5];
    const float* b_off  = (const float*)d_in[6];
    const float* W_attn = (const float*)d_in[7];
    const float* b_attn = (const float*)d_in[8];
    const float* W_val  = (const float*)d_in[9];
    const float* b_val  = (const float*)d_in[10];
    const float* W_out  = (const float*)d_in[11];
    const float* b_out  = (const float*)d_in[12];
    float* out = (float*)d_out;

    // Workspace layout:
    //   gqp   : float [16384*384]
    //   biasq : float [384]
    //   mid   : bf16  [16384*256]
    //   vpb   : bf16  [4*8*21760*32]
    //   Wt    : bf16  [229376]
    float*  gqp   = (float*)d_ws;
    float*  biasq = gqp + (size_t)16384 * 384;
    __bf16* mid   = (__bf16*)(biasq + 384);
    __bf16* vpb   = mid + (size_t)16384 * 256;
    __bf16* Wt    = vpb + (size_t)BB * 8 * NN * 32;
    __bf16* Wt_val = Wt;
    __bf16* Wt_q   = Wt + 65536;       // [384][256]: attn rows 0..127, off rows 128..383
    __bf16* Wt_out = Wt + 163840;

    // 0) weights -> bf16 transposed (+ fused q-proj bias [b_attn | b_off])
    prep_weights<<<898, 256, 0, stream>>>(W_val, W_attn, W_off, W_out, b_attn, b_off, Wt, biasq);

    // 1) v_p = v @ W_val + b_val -> bf16 [B,8,N,32]  (1360 blocks, 2/CU)
    {
        dim3 grid(1, 340, BB);
        gemm_ws<float, 256, 1><<<grid, 512, 0, stream>>>(v, Wt_val, b_val, vpb, NN, 0);
    }
    // 2) fused q-proj: [attn logits | offsets] = q @ Wq + biasq -> gqp [16384,384]
    //    3 feature-slices of 128 cols -> 768 blocks
    {
        dim3 grid(3, 256, 1);
        gemm_ws<float, 128, 0><<<grid, 512, 0, stream>>>(q, Wt_q, biasq, gqp, BB * QQ, 384);
    }
    // 3) softmax + bilinear sampling -> mid bf16 [B*Q,256]
    sampler<<<BB * QQ, 512, 0, stream>>>(vpb, gqp, p, mid);
    // 4) out = mid @ W_out + b_out -> [B,Q,256]  (2 slices -> 512 blocks)
    {
        dim3 grid(2, 256, 1);
        gemm_ws<__bf16, 128, 0><<<grid, 512, 0, stream>>>(mid, Wt_out, b_out, out, BB * QQ, 256);
    }
}

// Round 3
// 246.480 us; speedup vs baseline: 1.0253x; 1.0006x over previous
//
#include <hip/hip_runtime.h>
#include <cstddef>

// Problem constants (fixed by setup_inputs)
#define BB 4
#define QQ 4096
#define MM 8
#define NN 21760

typedef __bf16 bf16_8 __attribute__((ext_vector_type(8)));
typedef __bf16 bf16_4 __attribute__((ext_vector_type(4)));
typedef float  floatx4 __attribute__((ext_vector_type(4)));

// ---------------------------------------------------------------------------
// Weight prep: fp32 W[K][N] -> bf16 Wt[N][K].
// Wt layout (bf16): Wval[256x256] | Wq[384x256] (attn 0..127 | off 128..383) |
//                   Wout[256x256].  Also biasq[384] = [b_attn | b_off] fp32.
// ---------------------------------------------------------------------------
__global__ __launch_bounds__(256) void prep_weights(
    const float* __restrict__ Wv, const float* __restrict__ Wa,
    const float* __restrict__ Wo, const float* __restrict__ Wu,
    const float* __restrict__ ba, const float* __restrict__ bo,
    __bf16* __restrict__ Wt, float* __restrict__ biasq)
{
    const int gid = blockIdx.x * 256 + threadIdx.x;
    if (gid < 65536) {
        const int n = gid >> 8, k = gid & 255;
        Wt[gid] = (__bf16)Wv[k * 256 + n];
    } else if (gid < 163840) {
        const int o = gid - 65536;
        const int n = o >> 8, k = o & 255;
        Wt[gid] = (__bf16)(n < 128 ? Wa[k * 128 + n] : Wo[k * 256 + (n - 128)]);
    } else if (gid < 229376) {
        const int o = gid - 163840;
        const int n = o >> 8, k = o & 255;
        Wt[gid] = (__bf16)Wu[k * 256 + n];
    } else if (gid < 229760) {
        const int j = gid - 229376;
        biasq[j] = (j < 128) ? ba[j] : bo[j - 128];
    }
}

// ---------------------------------------------------------------------------
// Fused v_p + q-proj GEMM launch (independent: v_p reads v, qproj reads q).
// One 2128-block launch.  Blocks 0..767: q-projection (3 slices x 128 cols,
// fp32 store into gqp, ldc=384).  Blocks 768..2127: v_p (NCB=256, bf16
// store).  Short q-proj blocks are scheduled FIRST so the trailing partial
// block-wave is mostly cheap blocks (shorter drain tail); heterogeneous
// co-residency hides each block's serial weight-panel-load latency.
// Activation-stage loads are issued BEFORE weight loads so the
// ds_write/barrier critical path leads the vmem queue.
// ---------------------------------------------------------------------------
__global__ __launch_bounds__(512, 4) void gemm_vq(
    const float* __restrict__ v,
    const float* __restrict__ q,
    const __bf16* __restrict__ Wt,     // weight table base (Wval | Wq | Wout)
    const float* __restrict__ b_val,
    const float* __restrict__ biasq,   // [384]
    __bf16* __restrict__ vpb,          // [B,8,N,32] bf16
    float* __restrict__ gqp)           // [B*Q,384] fp32
{
    // XOR-swizzled activation tile: element (r, k) lives at column
    // ((k>>3) ^ (r&7))<<3 | (k&7).  32 KB (64 x 256 bf16).
    __shared__ __bf16 As[64][256];

    const int tid  = threadIdx.x;
    const int lane = tid & 63;
    const int wave = tid >> 6;
    const int quad = lane >> 4;
    const int l16  = lane & 15;
    const int flat = blockIdx.x;

    if (flat >= 768) {
        // ---------------- v_p: z in [0,4), 340 token tiles, NCB=256 --------
        const int f2     = flat - 768;
        const int z      = f2 / 340;
        const int token0 = (f2 - z * 340) * 64;
        const float* Af  = v + (size_t)z * NN * 256;

        // stage activation tile first (fp32 -> bf16, swizzled)
        #pragma unroll
        for (int c = 0; c < 8; ++c) {
            const int cid = c * 512 + tid;
            const int r   = cid >> 6;
            const int kc  = (cid & 63) * 4;
            const float4 av = *(const float4*)(Af + (size_t)(token0 + r) * 256 + kc);
            bf16_4 w;
            w[0] = (__bf16)av.x; w[1] = (__bf16)av.y;
            w[2] = (__bf16)av.z; w[3] = (__bf16)av.w;
            const int col = ((((kc >> 3) ^ (r & 7)) << 3) | (kc & 7));
            *(bf16_4*)&As[r][col] = w;
        }

        // weight panel -> VGPRs (issued after stage loads; latency drains
        // under the barrier + first ds_reads)
        bf16_8 wf[8][2];
        #pragma unroll
        for (int kk = 0; kk < 8; ++kk)
            #pragma unroll
            for (int j = 0; j < 2; ++j)
                wf[kk][j] = *(const bf16_8*)(Wt + (size_t)(wave * 32 + j * 16 + l16) * 256
                                              + kk * 32 + quad * 8);
        __syncthreads();

        floatx4 acc[2][4] = {};
        #pragma unroll
        for (int kk = 0; kk < 8; ++kk) {
            bf16_8 af[4];
            #pragma unroll
            for (int it = 0; it < 4; ++it)
                af[it] = *(const bf16_8*)&As[it * 16 + l16]
                                           [(((kk * 4 + quad) ^ (l16 & 7)) << 3)];
            #pragma unroll
            for (int j = 0; j < 2; ++j)
                #pragma unroll
                for (int it = 0; it < 4; ++it)
                    acc[j][it] = __builtin_amdgcn_mfma_f32_16x16x32_bf16(wf[kk][j], af[it], acc[j][it], 0, 0, 0);
        }

        #pragma unroll
        for (int j = 0; j < 2; ++j) {
            const int n0 = wave * 32 + j * 16 + quad * 4;
            const float4 b4 = *(const float4*)(b_val + n0);
            const int mh = n0 >> 5, dd = n0 & 31;
            #pragma unroll
            for (int it = 0; it < 4; ++it) {
                const int token = token0 + it * 16 + l16;
                bf16_4 ob;
                ob[0] = (__bf16)(acc[j][it][0] + b4.x);
                ob[1] = (__bf16)(acc[j][it][1] + b4.y);
                ob[2] = (__bf16)(acc[j][it][2] + b4.z);
                ob[3] = (__bf16)(acc[j][it][3] + b4.w);
                *(bf16_4*)(vpb + (((size_t)z * 8 + mh) * NN + token) * 32 + dd) = ob;
            }
        }
    } else {
        // ---------------- q-proj: 3 slices x 256 token tiles, NCB=128 ------
        const int o      = flat;
        const int slice  = o >> 8;           // 0..2
        const int token0 = (o & 255) * 64;
        const int col0   = slice * 128;
        const __bf16* Wb = Wt + 65536 + (size_t)col0 * 256;   // Wq rows

        #pragma unroll
        for (int c = 0; c < 8; ++c) {
            const int cid = c * 512 + tid;
            const int r   = cid >> 6;
            const int kc  = (cid & 63) * 4;
            const float4 av = *(const float4*)(q + (size_t)(token0 + r) * 256 + kc);
            bf16_4 w;
            w[0] = (__bf16)av.x; w[1] = (__bf16)av.y;
            w[2] = (__bf16)av.z; w[3] = (__bf16)av.w;
            const int col = ((((kc >> 3) ^ (r & 7)) << 3) | (kc & 7));
            *(bf16_4*)&As[r][col] = w;
        }

        bf16_8 wf[8];
        #pragma unroll
        for (int kk = 0; kk < 8; ++kk)
            wf[kk] = *(const bf16_8*)(Wb + (size_t)(wave * 16 + l16) * 256
                                       + kk * 32 + quad * 8);
        __syncthreads();

        floatx4 acc[4] = {};
        #pragma unroll
        for (int kk = 0; kk < 8; ++kk) {
            bf16_8 af[4];
            #pragma unroll
            for (int it = 0; it < 4; ++it)
                af[it] = *(const bf16_8*)&As[it * 16 + l16]
                                           [(((kk * 4 + quad) ^ (l16 & 7)) << 3)];
            #pragma unroll
            for (int it = 0; it < 4; ++it)
                acc[it] = __builtin_amdgcn_mfma_f32_16x16x32_bf16(wf[kk], af[it], acc[it], 0, 0, 0);
        }

        const int n0 = col0 + wave * 16 + quad * 4;
        const float4 b4 = *(const float4*)(biasq + n0);
        #pragma unroll
        for (int it = 0; it < 4; ++it) {
            const int token = token0 + it * 16 + l16;
            float4 ot;
            ot.x = acc[it][0] + b4.x;
            ot.y = acc[it][1] + b4.y;
            ot.z = acc[it][2] + b4.z;
            ot.w = acc[it][3] + b4.w;
            *(float4*)(gqp + (size_t)token * 384 + n0) = ot;
        }
    }
}

// ---------------------------------------------------------------------------
// Weight-stationary bf16 MFMA GEMM (used for the out-projection).
// One 64-token tile per block; feature slices via blockIdx.x.
// MODE 0: fp32 store at Cout[(z*tokens+token)*ldc + col]
// ---------------------------------------------------------------------------
template<typename AT, int NCB, int MODE>
__global__ __launch_bounds__(512, 4) void gemm_ws(
    const AT* __restrict__ A,
    const __bf16* __restrict__ Wn,     // [NCTOT][256] bf16 (n-major)
    const float* __restrict__ bias,    // [NCTOT] fp32
    void* __restrict__ Cout,
    int tokens, int ldc)
{
    constexpr int F  = NCB / 8;
    constexpr int NJ = F / 16;

    const int z    = blockIdx.z;
    const int col0 = blockIdx.x * NCB;
    const AT* Ab   = A + (size_t)z * tokens * 256;
    const __bf16* Wb = Wn + (size_t)col0 * 256;

    __shared__ __bf16 As[64][256];

    const int tid  = threadIdx.x;
    const int lane = tid & 63;
    const int wave = tid >> 6;
    const int quad = lane >> 4;
    const int l16  = lane & 15;
    const int wave_f = wave * F;

    // stage the 64x256 activation tile first
    const int token0 = blockIdx.y * 64;
    if (sizeof(AT) == 4) {
        const float* Af = (const float*)Ab;
        #pragma unroll
        for (int c = 0; c < 8; ++c) {
            const int cid = c * 512 + tid;
            const int r   = cid >> 6;
            const int kc  = (cid & 63) * 4;
            const float4 av = *(const float4*)(Af + (size_t)(token0 + r) * 256 + kc);
            bf16_4 w;
            w[0] = (__bf16)av.x; w[1] = (__bf16)av.y;
            w[2] = (__bf16)av.z; w[3] = (__bf16)av.w;
            const int col = ((((kc >> 3) ^ (r & 7)) << 3) | (kc & 7));
            *(bf16_4*)&As[r][col] = w;
        }
    } else {
        const __bf16* Ah = (const __bf16*)Ab;
        #pragma unroll
        for (int c = 0; c < 4; ++c) {
            const int cid = c * 512 + tid;
            const int r   = cid >> 5;
            const int kc  = (cid & 31) * 8;
            const bf16_8 av = *(const bf16_8*)(Ah + (size_t)(token0 + r) * 256 + kc);
            const int col = (((kc >> 3) ^ (r & 7)) << 3);
            *(bf16_8*)&As[r][col] = av;
        }
    }

    // weights -> VGPRs
    bf16_8 wf[8][NJ];
    #pragma unroll
    for (int kk = 0; kk < 8; ++kk)
        #pragma unroll
        for (int j = 0; j < NJ; ++j)
            wf[kk][j] = *(const bf16_8*)(Wb + (size_t)(wave_f + j * 16 + l16) * 256
                                          + kk * 32 + quad * 8);
    __syncthreads();

    floatx4 acc[NJ][4] = {};
    #pragma unroll
    for (int kk = 0; kk < 8; ++kk) {
        bf16_8 af[4];
        #pragma unroll
        for (int it = 0; it < 4; ++it)
            af[it] = *(const bf16_8*)&As[it * 16 + l16]
                                       [(((kk * 4 + quad) ^ (l16 & 7)) << 3)];
        #pragma unroll
        for (int j = 0; j < NJ; ++j)
            #pragma unroll
            for (int it = 0; it < 4; ++it)
                acc[j][it] = __builtin_amdgcn_mfma_f32_16x16x32_bf16(wf[kk][j], af[it], acc[j][it], 0, 0, 0);
    }

    #pragma unroll
    for (int j = 0; j < NJ; ++j) {
        const int n0 = col0 + wave_f + j * 16 + quad * 4;
        const float4 b4 = *(const float4*)(bias + n0);
        #pragma unroll
        for (int it = 0; it < 4; ++it) {
            const int token = token0 + it * 16 + l16;
            const float v0 = acc[j][it][0] + b4.x;
            const float v1 = acc[j][it][1] + b4.y;
            const float v2 = acc[j][it][2] + b4.z;
            const float v3 = acc[j][it][3] + b4.w;
            if (MODE == 0) {
                float4 o; o.x = v0; o.y = v1; o.z = v2; o.w = v3;
                *(float4*)((float*)Cout + ((size_t)z * tokens + token) * ldc + n0) = o;
            } else {
                const int mh = n0 >> 5, dd = n0 & 31;
                bf16_4 ob;
                ob[0] = (__bf16)v0; ob[1] = (__bf16)v1; ob[2] = (__bf16)v2; ob[3] = (__bf16)v3;
                *(bf16_4*)((__bf16*)Cout + (((size_t)z * 8 + mh) * NN + token) * 32 + dd) = ob;
            }
        }
    }
}

// ---------------------------------------------------------------------------
// Fused softmax + bilinear sampling: 4-lanes-per-row gather +
// halving-tree shuffle reduction.  Block = 512 threads = 8 waves (wave = head).
// ---------------------------------------------------------------------------
__device__ __forceinline__ float bflo(unsigned u) { return __uint_as_float(u << 16); }
__device__ __forceinline__ float bfhi(unsigned u) { return __uint_as_float(u & 0xffff0000u); }

__global__ __launch_bounds__(512) void sampler(
    const __bf16* __restrict__ vp,    // [B,8,N,32] bf16
    const float* __restrict__ gqp,    // [B*Q,384]: 0..127 attn logits, 128..383 offsets
    const float* __restrict__ pref,   // [B*Q,4,2]
    __bf16* __restrict__ mid)         // [B*Q,256] bf16
{
    const int t    = threadIdx.x;
    const int m    = t >> 6;
    const int lane = t & 63;
    const int s    = lane >> 2;     // sample 0..15
    const int c    = lane & 3;      // 16B chunk 0..3
    const int l    = s >> 2;        // level
    const int bq   = blockIdx.x;
    const int b    = bq >> 12;      // Q = 4096

    const int   Hi = 128 >> l;      // 128,64,32,16 (square levels)
    const float Hf = (float)Hi;
    const int   base = (l == 0) ? 0 : (l == 1) ? 16384 : (l == 2) ? 20480 : 21504;

    // softmax over the 16 samples of this head (lane bits 2..5); logits O(1)
    const float logit = gqp[(size_t)bq * 384 + m * 16 + s];
    const float e = __expf(logit);
    float sum = e;
    #pragma unroll
    for (int k = 4; k < 64; k <<= 1) sum += __shfl_xor(sum, k, 64);
    const float a = e * __builtin_amdgcn_rcpf(sum);

    const float2 off = *(const float2*)(gqp + (size_t)bq * 384 + 128 + (m * 16 + s) * 2);
    const float2 pr  = *(const float2*)(pref + (size_t)bq * 8 + l * 2);

    const float x = fmaf(pr.x, Hf, off.x - 0.5f);
    const float y = fmaf(pr.y, Hf, off.y - 0.5f);
    const float x0f = floorf(x), y0f = floorf(y);
    const float lx = x - x0f, ly = y - y0f;
    const int x0 = (int)x0f, y0 = (int)y0f;
    const int cx0 = min(max(x0, 0), Hi - 1), cx1 = min(max(x0 + 1, 0), Hi - 1);
    const int cy0 = min(max(y0, 0), Hi - 1), cy1 = min(max(y0 + 1, 0), Hi - 1);
    const bool vx0 = (x0 >= 0) && (x0 < Hi), vx1 = (x0 + 1 >= 0) && (x0 + 1 < Hi);
    const bool vy0 = (y0 >= 0) && (y0 < Hi), vy1 = (y0 + 1 >= 0) && (y0 + 1 < Hi);
    const float w00 = a * (1.f - lx) * (1.f - ly) * ((vx0 && vy0) ? 1.f : 0.f);
    const float w10 = a * lx * (1.f - ly) * ((vx1 && vy0) ? 1.f : 0.f);
    const float w01 = a * (1.f - lx) * ly * ((vx0 && vy1) ? 1.f : 0.f);
    const float w11 = a * lx * ly * ((vx1 && vy1) ? 1.f : 0.f);

    const __bf16* vbase = vp + ((size_t)b * 8 + m) * NN * 32;
    const uint4 u00 = *((const uint4*)(vbase + (size_t)(base + cy0 * Hi + cx0) * 32) + c);
    const uint4 u10 = *((const uint4*)(vbase + (size_t)(base + cy0 * Hi + cx1) * 32) + c);
    const uint4 u01 = *((const uint4*)(vbase + (size_t)(base + cy1 * Hi + cx0) * 32) + c);
    const uint4 u11 = *((const uint4*)(vbase + (size_t)(base + cy1 * Hi + cx1) * 32) + c);

    float f[8];
    f[0] = w00*bflo(u00.x) + w10*bflo(u10.x) + w01*bflo(u01.x) + w11*bflo(u11.x);
    f[1] = w00*bfhi(u00.x) + w10*bfhi(u10.x) + w01*bfhi(u01.x) + w11*bfhi(u11.x);
    f[2] = w00*bflo(u00.y) + w10*bflo(u10.y) + w01*bflo(u01.y) + w11*bflo(u11.y);
    f[3] = w00*bfhi(u00.y) + w10*bfhi(u10.y) + w01*bfhi(u01.y) + w11*bfhi(u11.y);
    f[4] = w00*bflo(u00.z) + w10*bflo(u10.z) + w01*bflo(u01.z) + w11*bflo(u11.z);
    f[5] = w00*bfhi(u00.z) + w10*bfhi(u10.z) + w01*bfhi(u01.z) + w11*bfhi(u11.z);
    f[6] = w00*bflo(u00.w) + w10*bflo(u10.w) + w01*bflo(u01.w) + w11*bflo(u11.w);
    f[7] = w00*bfhi(u00.w) + w10*bfhi(u10.w) + w01*bfhi(u01.w) + w11*bfhi(u11.w);

    // Halving-tree reduction over the 16 samples (lane bits 2..5)
    const int b2 = (lane >> 2) & 1, b3 = (lane >> 3) & 1, b4i = (lane >> 4) & 1;
    #pragma unroll
    for (int j = 0; j < 4; ++j) {
        const float sel  = b2 ? f[j] : f[j + 4];
        const float recv = __shfl_xor(sel, 4, 64);
        f[j] = (b2 ? f[j + 4] : f[j]) + recv;
    }
    #pragma unroll
    for (int j = 0; j < 2; ++j) {
        const float sel  = b3 ? f[j] : f[j + 2];
        const float recv = __shfl_xor(sel, 8, 64);
        f[j] = (b3 ? f[j + 2] : f[j]) + recv;
    }
    {
        const float sel  = b4i ? f[0] : f[1];
        const float recv = __shfl_xor(sel, 16, 64);
        f[0] = (b4i ? f[1] : f[0]) + recv;
    }
    f[0] += __shfl_xor(f[0], 32, 64);

    if (!(lane & 32)) {
        const int chan = (c << 3) | (b2 << 2) | (b3 << 1) | b4i;
        mid[(size_t)bq * 256 + m * 32 + chan] = (__bf16)f[0];
    }
}

extern "C" void kernel_launch(void* const* d_in, const int* in_sizes, int n_in,
                              void* d_out, int out_size, void* d_ws, size_t ws_size,
                              hipStream_t stream) {
    const float* q      = (const float*)d_in[0];
    const float* p      = (const float*)d_in[1];
    const float* v      = (const float*)d_in[2];
    const float* W_off  = (const float*)d_in[5];
    const float* b_off  = (const float*)d_in[6];
    const float* W_attn = (const float*)d_in[7];
    const float* b_attn = (const float*)d_in[8];
    const float* W_val  = (const float*)d_in[9];
    const float* b_val  = (const float*)d_in[10];
    const float* W_out  = (const float*)d_in[11];
    const float* b_out  = (const float*)d_in[12];
    float* out = (float*)d_out;

    // Workspace layout:
    //   gqp   : float [16384*384]
    //   biasq : float [384]
    //   mid   : bf16  [16384*256]
    //   vpb   : bf16  [4*8*21760*32]
    //   Wt    : bf16  [229376]
    float*  gqp   = (float*)d_ws;
    float*  biasq = gqp + (size_t)16384 * 384;
    __bf16* mid   = (__bf16*)(biasq + 384);
    __bf16* vpb   = mid + (size_t)16384 * 256;
    __bf16* Wt    = vpb + (size_t)BB * 8 * NN * 32;
    __bf16* Wt_out = Wt + 163840;

    // 0) weights -> bf16 transposed (+ fused q-proj bias [b_attn | b_off])
    prep_weights<<<898, 256, 0, stream>>>(W_val, W_attn, W_off, W_out, b_attn, b_off, Wt, biasq);

    // 1) fused v_p + q-proj: 768 + 1360 = 2128 blocks, one launch
    gemm_vq<<<2128, 512, 0, stream>>>(v, q, Wt, b_val, biasq, vpb, gqp);

    // 2) softmax + bilinear sampling -> mid bf16 [B*Q,256]
    sampler<<<BB * QQ, 512, 0, stream>>>(vpb, gqp, p, mid);

    // 3) out = mid @ W_out + b_out -> [B,Q,256]  (2 slices -> 512 blocks)
    {
        dim3 grid(2, 256, 1);
        gemm_ws<__bf16, 128, 0><<<grid, 512, 0, stream>>>(mid, Wt_out, b_out, out, BB * QQ, 256);
    }
}